// Round 4
// baseline (231951.416 us; speedup 1.0000x reference)
//
#include <hip/hip_runtime.h>
#include <cstdint>
#include <cstddef>

#define SEQ   8192
#define HD    2048
#define IND   16
#define NBLK  128   // one block per CU; each owns 16 hidden units
#define NTHR  512   // 8 waves; wave w owns units {b*16+2w, b*16+2w+1} (8 rows)
#define NSLOT 1024  // u64 slots per parity: lo32 = 2xfp16 h-pair, hi32 = tag

typedef _Float16 h2  __attribute__((ext_vector_type(2)));
typedef unsigned u32x4 __attribute__((ext_vector_type(4)));

union paircvt { h2 v; unsigned u; };

__device__ __forceinline__ float fdot2f(h2 a, h2 b, float c) {
#if defined(__has_builtin)
#if __has_builtin(__builtin_amdgcn_fdot2)
    return __builtin_amdgcn_fdot2(a, b, c, false);
#else
    return c + (float)a.x * (float)b.x + (float)a.y * (float)b.y;
#endif
#else
    return c + (float)a.x * (float)b.x + (float)a.y * (float)b.y;
#endif
}

__device__ __forceinline__ float sigmoid_f(float x) {
    return 1.f / (1.f + __expf(-x));
}
__device__ __forceinline__ float tanh_f(float x) {
    float e = __expf(2.f * x);
    return 1.f - 2.f / (e + 1.f);
}

// Persistent LSTM, round 4: BARRIER-FREE step.
// Lane L needs exactly h cols [32L, 32L+32) = slots [16L, 16L+16) = 128 B
// contiguous. So each lane polls its own 8 x dwordx4 (tag+pair interleaved):
// when all 16 tags == t, the h fragments are already in the registers the
// fdot2s consume. This deletes R3's entire ds_write -> barrier -> ds_read
// staging chain (~1000+ cyc serial/step). No __shared__ at all in the step.
// Parity reuse stays safe: slot S is rewritten with tag t+2 only after S's
// owner observed every wave's t+1 publish, and each wave publishes t+1 only
// after consuming all its t slots.
__global__ __launch_bounds__(NTHR, 1) void lstm_persist(
    const float* __restrict__ sa,    // [SEQ, IND]
    const float* __restrict__ W_ih,  // [4*HD, IND]
    const float* __restrict__ W_hh,  // [4*HD, HD]
    const float* __restrict__ b_ih,  // [4*HD]
    const float* __restrict__ b_hh,  // [4*HD]
    unsigned long long* __restrict__ hmsg,  // [2][NSLOT] tagged slots (zeroed)
    _Float16* __restrict__ hs16)     // [SEQ, HD] h history (fp16)
{
    const int b   = blockIdx.x;
    const int tid = threadIdx.x;
    const int w   = tid >> 6;        // wave 0..7
    const int L   = tid & 63;        // lane

    const int ubase = b * 16 + 2 * w;   // first of this wave's 2 units

    // ---- one-time: W_hh fragment -> registers (fp16 pairs) ----
    // 8 rows (r: gate=r&3, unit=r>>2), lane L owns cols [32L, 32L+32)
    h2 wreg[8][16];
#pragma unroll
    for (int r = 0; r < 8; ++r) {
        const int row = (r & 3) * HD + ubase + (r >> 2);
        const float4* Wr = (const float4*)(W_hh + (size_t)row * HD + L * 32);
#pragma unroll
        for (int q = 0; q < 8; ++q) {
            float4 f = Wr[q];
            h2 lo; lo.x = (_Float16)f.x; lo.y = (_Float16)f.y;
            h2 hi; hi.x = (_Float16)f.z; hi.y = (_Float16)f.w;
            wreg[r][2 * q]     = lo;
            wreg[r][2 * q + 1] = hi;
        }
    }
    // W_ih row + bias for the row this lane ends up holding (r = L&7)
    const int rowL = (L & 3) * HD + ubase + ((L >> 2) & 1);
    float wih[IND];
    {
        const float4* Wi = (const float4*)(W_ih + (size_t)rowL * IND);
#pragma unroll
        for (int q = 0; q < 4; ++q) {
            float4 f = Wi[q];
            wih[4 * q]     = f.x;
            wih[4 * q + 1] = f.y;
            wih[4 * q + 2] = f.z;
            wih[4 * q + 3] = f.w;
        }
    }
    const float bias = b_ih[rowL] + b_hh[rowL];

    // cell state: lanes with (L&4)==0 hold c of unit0, (L&4)==4 -> unit1
    float c = 0.f;

    for (unsigned t = 0; t < SEQ; ++t) {
        // ---- sa[t]: uniform loads issued before the poll (hidden) ----
        float sareg[IND];
        {
            const float* sat = sa + (size_t)t * IND;
#pragma unroll
            for (int k = 0; k < IND; ++k) sareg[k] = sat[k];
        }

        // ---- poll this lane's 16 slots (128 B) directly into regs ----
        const uint32_t* pp =
            (const uint32_t*)(hmsg + (size_t)(t & 1) * NSLOT + 16 * L);
        u32x4 m0, m1, m2, m3, m4, m5, m6, m7;
        for (;;) {
            asm volatile(
                "global_load_dwordx4 %0, %8, off sc1\n\t"
                "global_load_dwordx4 %1, %8, off offset:16 sc1\n\t"
                "global_load_dwordx4 %2, %8, off offset:32 sc1\n\t"
                "global_load_dwordx4 %3, %8, off offset:48 sc1\n\t"
                "global_load_dwordx4 %4, %8, off offset:64 sc1\n\t"
                "global_load_dwordx4 %5, %8, off offset:80 sc1\n\t"
                "global_load_dwordx4 %6, %8, off offset:96 sc1\n\t"
                "global_load_dwordx4 %7, %8, off offset:112 sc1\n\t"
                "s_waitcnt vmcnt(0)"
                : "=v"(m0), "=v"(m1), "=v"(m2), "=v"(m3),
                  "=v"(m4), "=v"(m5), "=v"(m6), "=v"(m7)
                : "v"(pp) : "memory");
            bool ok = (m0.y == t) & (m0.w == t) & (m1.y == t) & (m1.w == t) &
                      (m2.y == t) & (m2.w == t) & (m3.y == t) & (m3.w == t) &
                      (m4.y == t) & (m4.w == t) & (m5.y == t) & (m5.w == t) &
                      (m6.y == t) & (m6.w == t) & (m7.y == t) & (m7.w == t);
            if (ok) break;
            __builtin_amdgcn_s_sleep(1);
        }

        // ---- unpack h pairs (even words of each dwordx4) ----
        h2 hv[16];
        {
            paircvt cv;
            cv.u = m0.x; hv[0]  = cv.v;  cv.u = m0.z; hv[1]  = cv.v;
            cv.u = m1.x; hv[2]  = cv.v;  cv.u = m1.z; hv[3]  = cv.v;
            cv.u = m2.x; hv[4]  = cv.v;  cv.u = m2.z; hv[5]  = cv.v;
            cv.u = m3.x; hv[6]  = cv.v;  cv.u = m3.z; hv[7]  = cv.v;
            cv.u = m4.x; hv[8]  = cv.v;  cv.u = m4.z; hv[9]  = cv.v;
            cv.u = m5.x; hv[10] = cv.v;  cv.u = m5.z; hv[11] = cv.v;
            cv.u = m6.x; hv[12] = cv.v;  cv.u = m6.z; hv[13] = cv.v;
            cv.u = m7.x; hv[14] = cv.v;  cv.u = m7.z; hv[15] = cv.v;
        }

        // ---- 8 rows x 32 cols of dot product per lane ----
        float p[8] = {0.f, 0.f, 0.f, 0.f, 0.f, 0.f, 0.f, 0.f};
#pragma unroll
        for (int r = 0; r < 8; ++r)
#pragma unroll
            for (int k = 0; k < 16; ++k)
                p[r] = fdot2f(wreg[r][k], hv[k], p[r]);

        // ---- merge-reduce: lane L ends with full sum of row (L&7) ----
        const bool h1 = (L & 1), h2b = (L & 2), h4 = (L & 4);
        float v0, v1, v2, v3;
        {
            float k0 = h1 ? p[1] : p[0], s0 = h1 ? p[0] : p[1];
            v0 = k0 + __shfl_xor(s0, 1, 64);
            float k1 = h1 ? p[3] : p[2], s1 = h1 ? p[2] : p[3];
            v1 = k1 + __shfl_xor(s1, 1, 64);
            float k2 = h1 ? p[5] : p[4], s2 = h1 ? p[4] : p[5];
            v2 = k2 + __shfl_xor(s2, 1, 64);
            float k3 = h1 ? p[7] : p[6], s3 = h1 ? p[6] : p[7];
            v3 = k3 + __shfl_xor(s3, 1, 64);
        }
        float w0, w1;
        {
            float k0 = h2b ? v1 : v0, s0 = h2b ? v0 : v1;
            w0 = k0 + __shfl_xor(s0, 2, 64);
            float k1 = h2b ? v3 : v2, s1 = h2b ? v2 : v3;
            w1 = k1 + __shfl_xor(s1, 2, 64);
        }
        float tot;
        {
            float k0 = h4 ? w1 : w0, s0 = h4 ? w0 : w1;
            tot = k0 + __shfl_xor(s0, 4, 64);
        }
        tot += __shfl_xor(tot, 8, 64);
        tot += __shfl_xor(tot, 16, 64);
        tot += __shfl_xor(tot, 32, 64);

        // x-projection (input + biases) for row (L&7)
        float xp = bias;
#pragma unroll
        for (int k = 0; k < IND; ++k) xp += sareg[k] * wih[k];
        tot += xp;

        // ---- gates: all intra-wave (width-8 shuffles) ----
        const int ub4 = L & 4;   // 0 -> unit0 rows 0..3, 4 -> unit1 rows 4..7
        float gi = __shfl(tot, ub4 + 0, 8);
        float gf = __shfl(tot, ub4 + 1, 8);
        float gg = __shfl(tot, ub4 + 2, 8);
        float go = __shfl(tot, ub4 + 3, 8);
        float ii = sigmoid_f(gi);
        float ff = sigmoid_f(gf);
        float g  = tanh_f(gg);
        float oo = sigmoid_f(go);
        c = ff * c + ii * g;
        float h = oo * tanh_f(c);
        float hO = __shfl_xor(h, 4, 64);   // lane0: unit1's h (from lane4)

        if (L == 0) {
            paircvt pk;
            pk.v.x = (_Float16)h;    // unit ubase
            pk.v.y = (_Float16)hO;   // unit ubase+1
            ((unsigned*)hs16)[(size_t)t * (HD / 2) + b * 8 + w] = pk.u;
            unsigned long long msg =
                ((unsigned long long)(t + 1) << 32) | (unsigned long long)pk.u;
            __hip_atomic_store(&hmsg[(size_t)((t + 1) & 1) * NSLOT + b * 8 + w],
                               msg, __ATOMIC_RELAXED, __HIP_MEMORY_SCOPE_AGENT);
        }
    }
}

// Output projection: out[t,0:3] = hs[t]·W_uvw^T + b_uvw,
//                    out[t,3:6] = hs[t]·W_pqr^T + b_pqr
__global__ __launch_bounds__(256) void out_proj_kernel(
    const _Float16* __restrict__ hs16,
    const float* __restrict__ W_uvw, const float* __restrict__ b_uvw,
    const float* __restrict__ W_pqr, const float* __restrict__ b_pqr,
    float* __restrict__ out)
{
    __shared__ float Ws[6 * HD];
    const int tid = threadIdx.x;
    for (int i = tid; i < 3 * HD; i += 256) Ws[i] = W_uvw[i];
    for (int i = tid; i < 3 * HD; i += 256) Ws[3 * HD + i] = W_pqr[i];
    __syncthreads();

    const int w = tid >> 6, L = tid & 63;
#pragma unroll
    for (int r = 0; r < 4; ++r) {
        const int t = blockIdx.x * 16 + w * 4 + r;
        const _Float16* hrow = hs16 + (size_t)t * HD;
        float acc[6] = {0.f, 0.f, 0.f, 0.f, 0.f, 0.f};
        for (int cidx = L; cidx < HD; cidx += 64) {
            float hval = (float)hrow[cidx];
#pragma unroll
            for (int j = 0; j < 6; ++j) acc[j] += hval * Ws[j * HD + cidx];
        }
#pragma unroll
        for (int j = 0; j < 6; ++j) {
#pragma unroll
            for (int d = 1; d < 64; d <<= 1)
                acc[j] += __shfl_xor(acc[j], d, 64);
        }
        if (L == 0) {
#pragma unroll
            for (int j = 0; j < 6; ++j)
                out[(size_t)t * 6 + j] =
                    acc[j] + (j < 3 ? b_uvw[j] : b_pqr[j - 3]);
        }
    }
}

extern "C" void kernel_launch(void* const* d_in, const int* in_sizes, int n_in,
                              void* d_out, int out_size, void* d_ws, size_t ws_size,
                              hipStream_t stream) {
    (void)in_sizes; (void)n_in; (void)out_size; (void)ws_size;

    const float* sa    = (const float*)d_in[0];
    const float* W_ih  = (const float*)d_in[1];
    const float* W_hh  = (const float*)d_in[2];
    const float* b_ih  = (const float*)d_in[3];
    const float* b_hh  = (const float*)d_in[4];
    const float* W_uvw = (const float*)d_in[5];
    const float* b_uvw = (const float*)d_in[6];
    const float* W_pqr = (const float*)d_in[7];
    const float* b_pqr = (const float*)d_in[8];
    float* out = (float*)d_out;

    // workspace: [hs16: SEQ*HD*2 B = 32 MB][hmsg: 2*NSLOT*8 B = 16 KB]
    char* ws = (char*)d_ws;
    _Float16* hs16 = (_Float16*)ws;
    unsigned long long* hmsg =
        (unsigned long long*)(ws + (size_t)SEQ * HD * 2);

    // zero tags+values: tag 0 == "h_0 = 0 is ready" for parity-0 buffer
    hipMemsetAsync(hmsg, 0, (size_t)2 * NSLOT * 8, stream);

    hipLaunchKernelGGL(lstm_persist, dim3(NBLK), dim3(NTHR), 0, stream,
                       sa, W_ih, W_hh, b_ih, b_hh, hmsg, hs16);
    hipLaunchKernelGGL(out_proj_kernel, dim3(SEQ / 16), dim3(256), 0, stream,
                       hs16, W_uvw, b_uvw, W_pqr, b_pqr, out);
}

// Round 5
// 25786.676 us; speedup vs baseline: 8.9950x; 8.9950x over previous
//
#include <hip/hip_runtime.h>
#include <cstdint>
#include <cstddef>

#define SEQ   8192
#define HD    2048
#define IND   16
#define NBLK  256   // one block per CU; each owns 8 hidden units
#define NTHR  256   // 4 waves = 1 wave/SIMD (no VALU issue contention);
                    // wave w owns units {b*8+2w, b*8+2w+1} = 8 rows
#define NSLOT 1024  // u64 slots per parity: lo32 = 2xfp16 h-pair, hi32 = tag

typedef _Float16 h2  __attribute__((ext_vector_type(2)));
typedef unsigned u32x4 __attribute__((ext_vector_type(4)));

union paircvt { h2 v; unsigned u; };

__device__ __forceinline__ float fdot2f(h2 a, h2 b, float c) {
#if defined(__has_builtin)
#if __has_builtin(__builtin_amdgcn_fdot2)
    return __builtin_amdgcn_fdot2(a, b, c, false);
#else
    return c + (float)a.x * (float)b.x + (float)a.y * (float)b.y;
#endif
#else
    return c + (float)a.x * (float)b.x + (float)a.y * (float)b.y;
#endif
}

__device__ __forceinline__ float sigmoid_f(float x) {
    return 1.f / (1.f + __expf(-x));
}
__device__ __forceinline__ float tanh_f(float x) {
    float e = __expf(2.f * x);
    return 1.f - 2.f / (e + 1.f);
}

// Persistent LSTM, round 5.
//  - 256 blocks x 256 thr: 4 waves/CU = 1 wave/SIMD. R2->R3 A/B showed
//    2 waves/SIMD doubles compute wall-time (~+1100 cyc/step); this removes
//    that contention while keeping R3's intra-wave gates (ONE barrier).
//  - Poll: 2 DENSE dwordx4/thread (R4's 128B-per-lane poll was 32x line-
//    amplified on the L2-bypass path -> 10x regression; density is load-
//    bearing). s_sleep(1) backoff restored (R3 hot-spin hurt).
//  - LDS exchange XOR-swizzled: writes and reads both <=2-way (free, m136).
//  - Publish per-wave-when-done: 1x 8B device-scope store, lane 0.
__global__ __launch_bounds__(NTHR, 1) void lstm_persist(
    const float* __restrict__ sa,    // [SEQ, IND]
    const float* __restrict__ W_ih,  // [4*HD, IND]
    const float* __restrict__ W_hh,  // [4*HD, HD]
    const float* __restrict__ b_ih,  // [4*HD]
    const float* __restrict__ b_hh,  // [4*HD]
    unsigned long long* __restrict__ hmsg,  // [2][NSLOT] tagged slots (zeroed)
    _Float16* __restrict__ hs16)     // [SEQ, HD] h history (fp16)
{
    const int b   = blockIdx.x;
    const int tid = threadIdx.x;
    const int w   = tid >> 6;        // wave 0..3
    const int L   = tid & 63;        // lane

    __shared__ h2 hh2[16 * 64];      // h_t pairs, XOR-swizzled [k][row^2k]

    const int ubase = b * 8 + 2 * w; // first of this wave's 2 units

    // ---- one-time: W_hh fragment -> registers (fp16 pairs) ----
    // 8 rows (r: gate=r&3, unit=r>>2), lane L owns cols [32L, 32L+32)
    h2 wreg[8][16];
#pragma unroll
    for (int r = 0; r < 8; ++r) {
        const int row = (r & 3) * HD + ubase + (r >> 2);
        const float4* Wr = (const float4*)(W_hh + (size_t)row * HD + L * 32);
#pragma unroll
        for (int q = 0; q < 8; ++q) {
            float4 f = Wr[q];
            h2 lo; lo.x = (_Float16)f.x; lo.y = (_Float16)f.y;
            h2 hi; hi.x = (_Float16)f.z; hi.y = (_Float16)f.w;
            wreg[r][2 * q]     = lo;
            wreg[r][2 * q + 1] = hi;
        }
    }
    // W_ih row + bias for the row this lane ends up holding (r = L&7)
    const int rowL = (L & 3) * HD + ubase + ((L >> 2) & 1);
    float wih[IND];
    {
        const float4* Wi = (const float4*)(W_ih + (size_t)rowL * IND);
#pragma unroll
        for (int q = 0; q < 4; ++q) {
            float4 f = Wi[q];
            wih[4 * q]     = f.x;
            wih[4 * q + 1] = f.y;
            wih[4 * q + 2] = f.z;
            wih[4 * q + 3] = f.w;
        }
    }
    const float bias = b_ih[rowL] + b_hh[rowL];

    // cell state: lanes with (L&4)==0 hold c of unit0, (L&4)==4 -> unit1
    float c = 0.f;

    for (unsigned t = 0; t < SEQ; ++t) {
        // ---- sa[t]: uniform loads issued before the poll (hidden) ----
        float sareg[IND];
        {
            const float* sat = sa + (size_t)t * IND;
#pragma unroll
            for (int k = 0; k < IND; ++k) sareg[k] = sat[k];
        }

        // ---- poll 4 slots: {2tid, 2tid+1} and {512+2tid, 512+2tid+1} ----
        // two dense dwordx4 (each inst: contiguous 1 KB per wave), one drain
        const uint32_t* base =
            (const uint32_t*)(hmsg + (size_t)(t & 1) * NSLOT);
        const uint32_t* pp0 = base + 4 * tid;
        const uint32_t* pp1 = base + 1024 + 4 * tid;
        u32x4 m0, m1;
        for (;;) {
            asm volatile(
                "global_load_dwordx4 %0, %2, off sc1\n\t"
                "global_load_dwordx4 %1, %3, off sc1\n\t"
                "s_waitcnt vmcnt(0)"
                : "=v"(m0), "=v"(m1)
                : "v"(pp0), "v"(pp1) : "memory");
            bool ok = (m0.y == t) & (m0.w == t) & (m1.y == t) & (m1.w == t);
            if (ok) break;
            __builtin_amdgcn_s_sleep(1);
        }

        // ---- stage 4 pairs into swizzled LDS ----
        {
            paircvt cv;
            const int pa = 2 * tid, pb = 2 * tid + 1;
            const int pc = 512 + 2 * tid, pd = 513 + 2 * tid;
            cv.u = m0.x;
            hh2[(pa & 15) * 64 + (((pa >> 4) ^ (2 * (pa & 15))) & 63)] = cv.v;
            cv.u = m0.z;
            hh2[(pb & 15) * 64 + (((pb >> 4) ^ (2 * (pb & 15))) & 63)] = cv.v;
            cv.u = m1.x;
            hh2[(pc & 15) * 64 + (((pc >> 4) ^ (2 * (pc & 15))) & 63)] = cv.v;
            cv.u = m1.z;
            hh2[(pd & 15) * 64 + (((pd >> 4) ^ (2 * (pd & 15))) & 63)] = cv.v;
        }
        __syncthreads();

        // ---- read this lane's 16 pairs (cols [32L, 32L+32)) ----
        h2 hv[16];
#pragma unroll
        for (int k = 0; k < 16; ++k)
            hv[k] = hh2[k * 64 + ((L ^ (2 * k)) & 63)];

        // ---- 8 rows x 32 cols of dot product per lane ----
        float p[8] = {0.f, 0.f, 0.f, 0.f, 0.f, 0.f, 0.f, 0.f};
#pragma unroll
        for (int r = 0; r < 8; ++r)
#pragma unroll
            for (int k = 0; k < 16; ++k)
                p[r] = fdot2f(wreg[r][k], hv[k], p[r]);

        // ---- merge-reduce: lane L ends with full sum of row (L&7) ----
        const bool h1 = (L & 1), h2b = (L & 2), h4 = (L & 4);
        float v0, v1, v2, v3;
        {
            float k0 = h1 ? p[1] : p[0], s0 = h1 ? p[0] : p[1];
            v0 = k0 + __shfl_xor(s0, 1, 64);
            float k1 = h1 ? p[3] : p[2], s1 = h1 ? p[2] : p[3];
            v1 = k1 + __shfl_xor(s1, 1, 64);
            float k2 = h1 ? p[5] : p[4], s2 = h1 ? p[4] : p[5];
            v2 = k2 + __shfl_xor(s2, 1, 64);
            float k3 = h1 ? p[7] : p[6], s3 = h1 ? p[6] : p[7];
            v3 = k3 + __shfl_xor(s3, 1, 64);
        }
        float w0, w1;
        {
            float k0 = h2b ? v1 : v0, s0 = h2b ? v0 : v1;
            w0 = k0 + __shfl_xor(s0, 2, 64);
            float k1 = h2b ? v3 : v2, s1 = h2b ? v2 : v3;
            w1 = k1 + __shfl_xor(s1, 2, 64);
        }
        float tot;
        {
            float k0 = h4 ? w1 : w0, s0 = h4 ? w0 : w1;
            tot = k0 + __shfl_xor(s0, 4, 64);
        }
        tot += __shfl_xor(tot, 8, 64);
        tot += __shfl_xor(tot, 16, 64);
        tot += __shfl_xor(tot, 32, 64);

        // x-projection (input + biases) for row (L&7)
        float xp = bias;
#pragma unroll
        for (int k = 0; k < IND; ++k) xp += sareg[k] * wih[k];
        tot += xp;

        // ---- gates: all intra-wave (width-8 shuffles) ----
        const int ub4 = L & 4;   // 0 -> unit0 rows 0..3, 4 -> unit1 rows 4..7
        float gi = __shfl(tot, ub4 + 0, 8);
        float gf = __shfl(tot, ub4 + 1, 8);
        float gg = __shfl(tot, ub4 + 2, 8);
        float go = __shfl(tot, ub4 + 3, 8);
        float ii = sigmoid_f(gi);
        float ff = sigmoid_f(gf);
        float g  = tanh_f(gg);
        float oo = sigmoid_f(go);
        c = ff * c + ii * g;
        float h = oo * tanh_f(c);
        float hO = __shfl_xor(h, 4, 64);   // lane0: unit1's h (from lane4)

        if (L == 0) {
            paircvt pk;
            pk.v.x = (_Float16)h;    // unit ubase
            pk.v.y = (_Float16)hO;   // unit ubase+1
            ((unsigned*)hs16)[(size_t)t * (HD / 2) + b * 4 + w] = pk.u;
            unsigned long long msg =
                ((unsigned long long)(t + 1) << 32) | (unsigned long long)pk.u;
            __hip_atomic_store(&hmsg[(size_t)((t + 1) & 1) * NSLOT + b * 4 + w],
                               msg, __ATOMIC_RELAXED, __HIP_MEMORY_SCOPE_AGENT);
        }
    }
}

// Output projection: out[t,0:3] = hs[t]·W_uvw^T + b_uvw,
//                    out[t,3:6] = hs[t]·W_pqr^T + b_pqr
__global__ __launch_bounds__(256) void out_proj_kernel(
    const _Float16* __restrict__ hs16,
    const float* __restrict__ W_uvw, const float* __restrict__ b_uvw,
    const float* __restrict__ W_pqr, const float* __restrict__ b_pqr,
    float* __restrict__ out)
{
    __shared__ float Ws[6 * HD];
    const int tid = threadIdx.x;
    for (int i = tid; i < 3 * HD; i += 256) Ws[i] = W_uvw[i];
    for (int i = tid; i < 3 * HD; i += 256) Ws[3 * HD + i] = W_pqr[i];
    __syncthreads();

    const int w = tid >> 6, L = tid & 63;
#pragma unroll
    for (int r = 0; r < 4; ++r) {
        const int t = blockIdx.x * 16 + w * 4 + r;
        const _Float16* hrow = hs16 + (size_t)t * HD;
        float acc[6] = {0.f, 0.f, 0.f, 0.f, 0.f, 0.f};
        for (int cidx = L; cidx < HD; cidx += 64) {
            float hval = (float)hrow[cidx];
#pragma unroll
            for (int j = 0; j < 6; ++j) acc[j] += hval * Ws[j * HD + cidx];
        }
#pragma unroll
        for (int j = 0; j < 6; ++j) {
#pragma unroll
            for (int d = 1; d < 64; d <<= 1)
                acc[j] += __shfl_xor(acc[j], d, 64);
        }
        if (L == 0) {
#pragma unroll
            for (int j = 0; j < 6; ++j)
                out[(size_t)t * 6 + j] =
                    acc[j] + (j < 3 ? b_uvw[j] : b_pqr[j - 3]);
        }
    }
}

extern "C" void kernel_launch(void* const* d_in, const int* in_sizes, int n_in,
                              void* d_out, int out_size, void* d_ws, size_t ws_size,
                              hipStream_t stream) {
    (void)in_sizes; (void)n_in; (void)out_size; (void)ws_size;

    const float* sa    = (const float*)d_in[0];
    const float* W_ih  = (const float*)d_in[1];
    const float* W_hh  = (const float*)d_in[2];
    const float* b_ih  = (const float*)d_in[3];
    const float* b_hh  = (const float*)d_in[4];
    const float* W_uvw = (const float*)d_in[5];
    const float* b_uvw = (const float*)d_in[6];
    const float* W_pqr = (const float*)d_in[7];
    const float* b_pqr = (const float*)d_in[8];
    float* out = (float*)d_out;

    // workspace: [hs16: SEQ*HD*2 B = 32 MB][hmsg: 2*NSLOT*8 B = 16 KB]
    char* ws = (char*)d_ws;
    _Float16* hs16 = (_Float16*)ws;
    unsigned long long* hmsg =
        (unsigned long long*)(ws + (size_t)SEQ * HD * 2);

    // zero tags+values: tag 0 == "h_0 = 0 is ready" for parity-0 buffer
    hipMemsetAsync(hmsg, 0, (size_t)2 * NSLOT * 8, stream);

    hipLaunchKernelGGL(lstm_persist, dim3(NBLK), dim3(NTHR), 0, stream,
                       sa, W_ih, W_hh, b_ih, b_hh, hmsg, hs16);
    hipLaunchKernelGGL(out_proj_kernel, dim3(SEQ / 16), dim3(256), 0, stream,
                       hs16, W_uvw, b_uvw, W_pqr, b_pqr, out);
}